// Round 9
// baseline (252.345 us; speedup 1.0000x reference)
//
#include <hip/hip_runtime.h>

#define NVEC (64*64*64)   // 262144 vectors
#define KCB 1024          // codebook size
#define DIM 64            // codebook dim

typedef __attribute__((ext_vector_type(8))) short s16x8;   // 8 x bf16
typedef __attribute__((ext_vector_type(4))) float f32x4;

#define MFMA16(A, B, C) __builtin_amdgcn_mfma_f32_16x16x32_bf16((A), (B), (C), 0, 0, 0)

// ws layout (bytes):
//      0 : uint counts[1024]            (ends 4096, pad to 4112)
//   4112 : float cnf[1024]              (ends 8208, pad to 8224)
//   8224 : ushort cbA[64][2][64][8]     A-frag layout of bf16(-2c), 131072 B, ends 139296
// 141568 : float wave_partials[4096]    (ends 157952) -- per-wave loss, NO atomics

__global__ __launch_bounds__(256) void vq_prep(const float* __restrict__ cb,
                                               unsigned short* __restrict__ cbA,
                                               float* __restrict__ cnf,
                                               unsigned int* __restrict__ counts) {
    int q = blockIdx.x * 256 + threadIdx.x;      // 0..8191
    if (q < 256) ((int4*)counts)[q] = int4{0, 0, 0, 0};   // re-zero AFTER diagnostics
    int t = q >> 7;
    int h = (q >> 6) & 1;
    int l = q & 63;
    int m = t * 16 + (l & 15);
    int d0 = h * 32 + ((l >> 4) & 3) * 8;
    const float* row = cb + (size_t)m * DIM + d0;
    unsigned short* dst = cbA + (size_t)q * 8;
    #pragma unroll
    for (int j = 0; j < 8; ++j) {
        float f = -2.0f * row[j];
        unsigned u = __float_as_uint(f);
        dst[j] = (unsigned short)((u + 0x7fffu + ((u >> 16) & 1u)) >> 16);  // RNE bf16
    }
    if (q < KCB) {
        const float* r2 = cb + (size_t)q * DIM;
        double s = 0.0;
        for (int d = 0; d < DIM; ++d) { double c = (double)r2[d]; s = fma(c, c, s); }
        cnf[q] = (float)s;
    }
}

// ===================== DIAGNOSTIC KERNELS (run BEFORE vq_prep; all ==========
// ===================== outputs overwritten by the real pipeline)   ==========

// memory path: x-load + convert + xnorm + out-write/atomics/partials, NO K-loop
__global__ __launch_bounds__(256, 4) void diag_mem(const float* __restrict__ inp,
                                                   const float* __restrict__ cb,
                                                   float* __restrict__ out,
                                                   float* __restrict__ partials,
                                                   unsigned int* __restrict__ counts) {
    const int tid = threadIdx.x, lane = tid & 63, w = tid >> 6;
    const int l15 = lane & 15, g = lane >> 4;
    const int vecbase = blockIdx.x * 256 + w * 64;

    float xnorm[4];
    #pragma unroll
    for (int v = 0; v < 4; ++v) {
        const float4* xp = (const float4*)(inp + (size_t)(vecbase + v * 16 + l15) * DIM);
        float4 a0 = xp[g * 2], a1 = xp[g * 2 + 1];
        float4 a2 = xp[8 + g * 2], a3 = xp[8 + g * 2 + 1];
        float f0[8] = {a0.x, a0.y, a0.z, a0.w, a1.x, a1.y, a1.z, a1.w};
        float f1[8] = {a2.x, a2.y, a2.z, a2.w, a3.x, a3.y, a3.z, a3.w};
        float xn = 0.f;
        unsigned w0[4], w1[4];
        #pragma unroll
        for (int p = 0; p < 4; ++p) {
            xn = fmaf(f0[2*p], f0[2*p], xn);
            xn = fmaf(f0[2*p+1], f0[2*p+1], xn);
            xn = fmaf(f1[2*p], f1[2*p], xn);
            xn = fmaf(f1[2*p+1], f1[2*p+1], xn);
            unsigned r0, r1;
            asm("v_cvt_pk_bf16_f32 %0, %1, %2" : "=v"(r0) : "v"(f0[2*p]), "v"(f0[2*p+1]));
            asm("v_cvt_pk_bf16_f32 %0, %1, %2" : "=v"(r1) : "v"(f1[2*p]), "v"(f1[2*p+1]));
            w0[p] = r0; w1[p] = r1;
        }
        asm volatile("" :: "v"(w0[0]), "v"(w0[1]), "v"(w0[2]), "v"(w0[3]),
                           "v"(w1[0]), "v"(w1[1]), "v"(w1[2]), "v"(w1[3]));  // keep converts
        xnorm[v] = xn;
    }

    int bidx[4];
    #pragma unroll
    for (int v = 0; v < 4; ++v) {
        unsigned b = (unsigned)(vecbase + v * 37 + lane * 11) & 1023u;
        asm volatile("" : "+v"(b));   // opaque synthetic index
        bidx[v] = (int)b;
        xnorm[v] += __shfl_xor(xnorm[v], 16);
        xnorm[v] += __shfl_xor(xnorm[v], 32);
    }

    float4* ob4 = (float4*)(out + (size_t)vecbase * DIM);
    float ls = 0.0f;
    #pragma unroll
    for (int v = 0; v < 4; ++v) {
        #pragma unroll
        for (int i = 0; i < 4; ++i) {
            int wv = i * 4 + g;
            int bk = __shfl(bidx[v], wv);
            float4 q = ((const float4*)(cb + (size_t)bk * DIM))[l15];
            ob4[(v * 16 + wv) * 16 + l15] = q;
        }
        if (g == 0) { atomicAdd(&counts[bidx[v]], 1u); ls += xnorm[v]; }
    }
    #pragma unroll
    for (int off = 32; off > 0; off >>= 1) ls += __shfl_xor(ls, off);
    if (lane == 0) partials[blockIdx.x * 4 + w] = ls;
}

// staging + barriers only
__global__ __launch_bounds__(256, 4) void diag_stage(const unsigned short* __restrict__ cbA,
                                                     float* __restrict__ partials) {
    __shared__ unsigned short bufS[2][4096];
    const int tid = threadIdx.x, lane = tid & 63, w = tid >> 6;
    const int4* gA = (const int4*)cbA;
    int4 s0 = gA[(2 * w) * 64 + lane];
    int4 s1 = gA[(2 * w + 1) * 64 + lane];
    ((int4*)bufS[0])[(2 * w) * 64 + lane] = s0;
    ((int4*)bufS[0])[(2 * w + 1) * 64 + lane] = s1;
    __syncthreads();
    int keep = 0;
    for (int c = 0; c < 16; ++c) {
        const int cur = c & 1;
        int4 n0 = {}, n1 = {};
        const bool have = (c < 15);
        if (have) {
            int rb = (c + 1) * 8;
            n0 = gA[(rb + 2 * w) * 64 + lane];
            n1 = gA[(rb + 2 * w + 1) * 64 + lane];
        }
        int4 r0 = ((const int4*)bufS[cur])[lane];   // minimal consume
        keep ^= r0.x ^ r0.w;
        if (have) {
            ((int4*)bufS[cur ^ 1])[(2 * w) * 64 + lane] = n0;
            ((int4*)bufS[cur ^ 1])[(2 * w + 1) * 64 + lane] = n1;
        }
        __syncthreads();
    }
    asm volatile("" :: "v"(keep));
    if (lane == 99) partials[blockIdx.x * 4 + w] = (float)keep;  // never true, anti-DCE belt
}

// staging + ds_read + MFMA (+ argmin iff DOMIN) with synthetic x
template <int DOMIN>
__global__ __launch_bounds__(256, 4) void diag_kloop(const unsigned short* __restrict__ cbA,
                                                     const float* __restrict__ cnf,
                                                     float* __restrict__ partials) {
    __shared__ unsigned short bufS[2][4096];
    __shared__ float cnS[KCB];
    const int tid = threadIdx.x, lane = tid & 63, w = tid >> 6;
    const int l15 = lane & 15, g = lane >> 4, gi = g * 4;
    (void)l15;
    const int4* gA = (const int4*)cbA;
    int4 s0 = gA[(2 * w) * 64 + lane];
    int4 s1 = gA[(2 * w + 1) * 64 + lane];
    float4 cnl = ((const float4*)cnf)[tid];

    s16x8 xb[4][2];
    #pragma unroll
    for (int v = 0; v < 4; ++v) {
        #pragma unroll
        for (int h = 0; h < 2; ++h) {
            unsigned q[4];
            #pragma unroll
            for (int p = 0; p < 4; ++p) {
                unsigned u = (unsigned)tid * 2654435761u + (unsigned)(v * 401 + h * 131 + p * 8191);
                asm volatile("" : "+v"(u));   // opaque synthetic bf16 pairs
                q[p] = u;
            }
            xb[v][h] = *(const s16x8*)q;
        }
    }

    ((int4*)bufS[0])[(2 * w) * 64 + lane] = s0;
    ((int4*)bufS[0])[(2 * w + 1) * 64 + lane] = s1;
    ((float4*)cnS)[tid] = cnl;
    __syncthreads();

    float best[4] = {3.4e38f, 3.4e38f, 3.4e38f, 3.4e38f};

    for (int c = 0; c < 16; ++c) {
        const int cur = c & 1;
        int4 n0 = {}, n1 = {};
        const bool have = (c < 15);
        if (have) {
            int rb = (c + 1) * 8;
            n0 = gA[(rb + 2 * w) * 64 + lane];
            n1 = gA[(rb + 2 * w + 1) * 64 + lane];
        }
        const s16x8* bf = (const s16x8*)bufS[cur];
        #pragma unroll
        for (int tt = 0; tt < 4; ++tt) {
            s16x8 A0 = bf[(tt * 2) * 64 + lane];
            s16x8 A1 = bf[(tt * 2 + 1) * 64 + lane];
            int t = c * 4 + tt;
            f32x4 cn4 = *(const f32x4*)(cnS + t * 16 + gi);
            f32x4 acc[4];
            #pragma unroll
            for (int v = 0; v < 4; ++v) acc[v] = cn4;
            #pragma unroll
            for (int v = 0; v < 4; ++v) acc[v] = MFMA16(A0, xb[v][0], acc[v]);
            #pragma unroll
            for (int v = 0; v < 4; ++v) acc[v] = MFMA16(A1, xb[v][1], acc[v]);
            if constexpr (DOMIN) {
                int kb = (t << 4) + gi;
                #pragma unroll
                for (int v = 0; v < 4; ++v) {
                    float p0 = __uint_as_float((__float_as_uint(acc[v][0]) & 0xFFFFFC00u) | (unsigned)(kb));
                    float p1 = __uint_as_float((__float_as_uint(acc[v][1]) & 0xFFFFFC00u) | (unsigned)(kb + 1));
                    float p2 = __uint_as_float((__float_as_uint(acc[v][2]) & 0xFFFFFC00u) | (unsigned)(kb + 2));
                    float p3 = __uint_as_float((__float_as_uint(acc[v][3]) & 0xFFFFFC00u) | (unsigned)(kb + 3));
                    float p01 = fminf(p0, p1), p23 = fminf(p2, p3);
                    best[v] = fminf(fminf(p01, p23), best[v]);
                }
            } else {
                #pragma unroll
                for (int v = 0; v < 4; ++v)
                    asm volatile("" :: "v"(acc[v][0]), "v"(acc[v][1]),
                                       "v"(acc[v][2]), "v"(acc[v][3]));  // keep MFMAs, zero VALU
            }
        }
        if (have) {
            ((int4*)bufS[cur ^ 1])[(2 * w) * 64 + lane] = n0;
            ((int4*)bufS[cur ^ 1])[(2 * w + 1) * 64 + lane] = n1;
        }
        __syncthreads();
    }

    if constexpr (DOMIN) {
        float ls = 0.f;
        #pragma unroll
        for (int v = 0; v < 4; ++v) {
            best[v] = fminf(best[v], __shfl_xor(best[v], 16));
            best[v] = fminf(best[v], __shfl_xor(best[v], 32));
            ls += best[v];
        }
        if (lane == 0) partials[blockIdx.x * 4 + w] = ls;
    }
}

// ===================== REAL PIPELINE (identical to round 8) =====================

__global__ __launch_bounds__(256, 4) void vq_main(const float* __restrict__ inp,
                                                  const unsigned short* __restrict__ cbA,
                                                  const float* __restrict__ cnf,
                                                  const float* __restrict__ cb,
                                                  float* __restrict__ out,
                                                  float* __restrict__ partials,
                                                  unsigned int* __restrict__ counts) {
    __shared__ unsigned short bufS[2][4096];
    __shared__ float cnS[KCB];

    const int tid  = threadIdx.x;
    const int lane = tid & 63;
    const int w    = tid >> 6;
    const int l15  = lane & 15;
    const int g    = lane >> 4;
    const int gi   = g * 4;
    const int vecbase = blockIdx.x * 256 + w * 64;

    const int4* __restrict__ gA = (const int4*)cbA;

    int4 s0 = gA[(2 * w) * 64 + lane];
    int4 s1 = gA[(2 * w + 1) * 64 + lane];
    float4 cnl = ((const float4*)cnf)[tid];

    s16x8 xb[4][2];
    float xnorm[4];
    #pragma unroll
    for (int v = 0; v < 4; ++v) {
        const float4* xp = (const float4*)(inp + (size_t)(vecbase + v * 16 + l15) * DIM);
        float4 a0 = xp[g * 2], a1 = xp[g * 2 + 1];
        float4 a2 = xp[8 + g * 2], a3 = xp[8 + g * 2 + 1];
        float f0[8] = {a0.x, a0.y, a0.z, a0.w, a1.x, a1.y, a1.z, a1.w};
        float f1[8] = {a2.x, a2.y, a2.z, a2.w, a3.x, a3.y, a3.z, a3.w};
        float xn = 0.f;
        unsigned w0[4], w1[4];
        #pragma unroll
        for (int p = 0; p < 4; ++p) {
            xn = fmaf(f0[2*p], f0[2*p], xn);
            xn = fmaf(f0[2*p+1], f0[2*p+1], xn);
            xn = fmaf(f1[2*p], f1[2*p], xn);
            xn = fmaf(f1[2*p+1], f1[2*p+1], xn);
            unsigned r0, r1;
            asm("v_cvt_pk_bf16_f32 %0, %1, %2" : "=v"(r0) : "v"(f0[2*p]), "v"(f0[2*p+1]));
            asm("v_cvt_pk_bf16_f32 %0, %1, %2" : "=v"(r1) : "v"(f1[2*p]), "v"(f1[2*p+1]));
            w0[p] = r0; w1[p] = r1;
        }
        xb[v][0] = *(const s16x8*)w0;
        xb[v][1] = *(const s16x8*)w1;
        xnorm[v] = xn;
    }

    ((int4*)bufS[0])[(2 * w) * 64 + lane] = s0;
    ((int4*)bufS[0])[(2 * w + 1) * 64 + lane] = s1;
    ((float4*)cnS)[tid] = cnl;
    __syncthreads();

    float best[4] = {3.4e38f, 3.4e38f, 3.4e38f, 3.4e38f};

    for (int c = 0; c < 16; ++c) {
        const int cur = c & 1;
        int4 n0 = {}, n1 = {};
        const bool have = (c < 15);
        if (have) {
            int rb = (c + 1) * 8;
            n0 = gA[(rb + 2 * w) * 64 + lane];
            n1 = gA[(rb + 2 * w + 1) * 64 + lane];
        }

        const s16x8* bf = (const s16x8*)bufS[cur];
        #pragma unroll
        for (int tt = 0; tt < 4; ++tt) {
            s16x8 A0 = bf[(tt * 2) * 64 + lane];
            s16x8 A1 = bf[(tt * 2 + 1) * 64 + lane];
            int t = c * 4 + tt;
            f32x4 cn4 = *(const f32x4*)(cnS + t * 16 + gi);

            f32x4 acc[4];
            #pragma unroll
            for (int v = 0; v < 4; ++v) acc[v] = cn4;
            #pragma unroll
            for (int v = 0; v < 4; ++v) acc[v] = MFMA16(A0, xb[v][0], acc[v]);
            #pragma unroll
            for (int v = 0; v < 4; ++v) acc[v] = MFMA16(A1, xb[v][1], acc[v]);

            int kb = (t << 4) + gi;
            #pragma unroll
            for (int v = 0; v < 4; ++v) {
                float p0 = __uint_as_float((__float_as_uint(acc[v][0]) & 0xFFFFFC00u) | (unsigned)(kb));
                float p1 = __uint_as_float((__float_as_uint(acc[v][1]) & 0xFFFFFC00u) | (unsigned)(kb + 1));
                float p2 = __uint_as_float((__float_as_uint(acc[v][2]) & 0xFFFFFC00u) | (unsigned)(kb + 2));
                float p3 = __uint_as_float((__float_as_uint(acc[v][3]) & 0xFFFFFC00u) | (unsigned)(kb + 3));
                float p01 = fminf(p0, p1), p23 = fminf(p2, p3);
                best[v] = fminf(fminf(p01, p23), best[v]);
            }
        }

        if (have) {
            ((int4*)bufS[cur ^ 1])[(2 * w) * 64 + lane] = n0;
            ((int4*)bufS[cur ^ 1])[(2 * w + 1) * 64 + lane] = n1;
        }
        __syncthreads();
    }

    int bidx[4];
    #pragma unroll
    for (int v = 0; v < 4; ++v) {
        best[v] = fminf(best[v], __shfl_xor(best[v], 16));
        best[v] = fminf(best[v], __shfl_xor(best[v], 32));
        xnorm[v] += __shfl_xor(xnorm[v], 16);
        xnorm[v] += __shfl_xor(xnorm[v], 32);
        bidx[v] = (int)(__float_as_uint(best[v]) & 1023u);
    }

    float4* ob4 = (float4*)(out + (size_t)vecbase * DIM);
    float ls = 0.0f;
    #pragma unroll
    for (int v = 0; v < 4; ++v) {
        #pragma unroll
        for (int i = 0; i < 4; ++i) {
            int wv = i * 4 + g;
            int bk = __shfl(bidx[v], wv);
            float4 q = ((const float4*)(cb + (size_t)bk * DIM))[l15];
            ob4[(v * 16 + wv) * 16 + l15] = q;
        }
        if (g == 0) {
            atomicAdd(&counts[bidx[v]], 1u);
            ls += best[v] + xnorm[v];
        }
    }

    #pragma unroll
    for (int off = 32; off > 0; off >>= 1) ls += __shfl_xor(ls, off);
    if (lane == 0) partials[blockIdx.x * 4 + w] = ls;
}

__global__ __launch_bounds__(256) void vq_finalize(float* __restrict__ out,
                                                   const float* __restrict__ partials,
                                                   const unsigned int* __restrict__ counts) {
    __shared__ double red[256];
    double s = 0.0;
    for (int i = threadIdx.x; i < 4096; i += 256) s += (double)partials[i];
    double h = 0.0;
    for (int k = threadIdx.x; k < KCB; k += 256) {
        double p = (double)counts[k] / (double)NVEC;
        h += p * log(p + 1e-10);
    }
    red[threadIdx.x] = s;
    __syncthreads();
    for (int t = 128; t > 0; t >>= 1) {
        if (threadIdx.x < t) red[threadIdx.x] += red[threadIdx.x + t];
        __syncthreads();
    }
    double loss_tot = red[0];
    __syncthreads();
    red[threadIdx.x] = h;
    __syncthreads();
    for (int t = 128; t > 0; t >>= 1) {
        if (threadIdx.x < t) red[threadIdx.x] += red[threadIdx.x + t];
        __syncthreads();
    }
    if (threadIdx.x == 0) {
        out[(size_t)NVEC * DIM]     = (float)(0.25 * loss_tot / (double)((size_t)NVEC * DIM));
        out[(size_t)NVEC * DIM + 1] = (float)exp(-red[0]);
    }
}

extern "C" void kernel_launch(void* const* d_in, const int* in_sizes, int n_in,
                              void* d_out, int out_size, void* d_ws, size_t ws_size,
                              hipStream_t stream) {
    const float* inp = (const float*)d_in[0];   // (64,64,64,64) f32
    const float* cb  = (const float*)d_in[1];   // (1024,64) f32
    float* out = (float*)d_out;

    char* ws = (char*)d_ws;
    unsigned int*   counts   = (unsigned int*)(ws + 0);
    float*          cnf      = (float*)(ws + 4112);
    unsigned short* cbA      = (unsigned short*)(ws + 8224);
    float*          partials = (float*)(ws + 141568);

    // ---- diagnostics first: everything they touch is rewritten by the real
    // pipeline below (out by vq_main, counts re-zeroed by vq_prep, partials
    // fully rewritten by vq_main). cbA/cnf contents during diagnostics are
    // timing-irrelevant (MFMA is data-independent).
    diag_mem<<<dim3(NVEC / 256), dim3(256), 0, stream>>>(inp, cb, out, partials, counts);
    diag_stage<<<dim3(NVEC / 256), dim3(256), 0, stream>>>(cbA, partials);
    diag_kloop<0><<<dim3(NVEC / 256), dim3(256), 0, stream>>>(cbA, cnf, partials);
    diag_kloop<1><<<dim3(NVEC / 256), dim3(256), 0, stream>>>(cbA, cnf, partials);

    // ---- real pipeline (identical to round 8) ----
    vq_prep<<<dim3(32), dim3(256), 0, stream>>>(cb, cbA, cnf, counts);
    vq_main<<<dim3(NVEC / 256), dim3(256), 0, stream>>>(inp, cbA, cnf, cb, out,
                                                        partials, counts);
    vq_finalize<<<dim3(1), dim3(256), 0, stream>>>(out, partials, counts);
}

// Round 10
// 124.676 us; speedup vs baseline: 2.0240x; 2.0240x over previous
//
#include <hip/hip_runtime.h>

#define NVEC (64*64*64)   // 262144 vectors
#define KCB 1024          // codebook size
#define DIM 64            // codebook dim

typedef __attribute__((ext_vector_type(8))) short s16x8;   // 8 x bf16
typedef __attribute__((ext_vector_type(4))) float f32x4;

#define MFMA16(A, B, C) __builtin_amdgcn_mfma_f32_16x16x32_bf16((A), (B), (C), 0, 0, 0)

// ws layout (bytes):
//      0 : uint counts[1024]            (ends 4096, pad to 4112)
//   4112 : float cnf[1024]              (ends 8208; K-loop prefetch over-reads up to
//                                        ~220B past the end into cbA head -- values
//                                        land in dead registers, never consumed)
//   8224 : ushort cbA[64][2][64][8]     A-frag layout of bf16(-2c), 131072 B, ends 139296
//          139296..147488 : prefetch over-read pad (tiles 64..67), value-irrelevant
// 147968 : float wave_partials[4096]    (ends 164352) -- per-wave loss, NO atomics

__global__ __launch_bounds__(256) void vq_prep(const float* __restrict__ cb,
                                               unsigned short* __restrict__ cbA,
                                               float* __restrict__ cnf,
                                               unsigned int* __restrict__ counts) {
    int q = blockIdx.x * 256 + threadIdx.x;      // 0..8191
    if (q < 256) ((int4*)counts)[q] = int4{0, 0, 0, 0};   // folded memset
    int t = q >> 7;
    int h = (q >> 6) & 1;
    int l = q & 63;
    int m = t * 16 + (l & 15);
    int d0 = h * 32 + ((l >> 4) & 3) * 8;
    const float* row = cb + (size_t)m * DIM + d0;
    unsigned short* dst = cbA + (size_t)q * 8;
    #pragma unroll
    for (int j = 0; j < 8; ++j) {
        float f = -2.0f * row[j];
        unsigned u = __float_as_uint(f);
        dst[j] = (unsigned short)((u + 0x7fffu + ((u >> 16) & 1u)) >> 16);  // RNE bf16
    }
    if (q < KCB) {
        const float* r2 = cb + (size_t)q * DIM;
        double s = 0.0;
        for (int d = 0; d < DIM; ++d) { double c = (double)r2[d]; s = fma(c, c, s); }
        cnf[q] = (float)s;
    }
}

__global__ __launch_bounds__(256, 4) void vq_main(const float* __restrict__ inp,
                                                  const unsigned short* __restrict__ cbA,
                                                  const float* __restrict__ cnf,
                                                  const float* __restrict__ cb,
                                                  float* __restrict__ out,
                                                  float* __restrict__ partials,
                                                  unsigned int* __restrict__ counts) {
    const int tid  = threadIdx.x;
    const int lane = tid & 63;
    const int w    = tid >> 6;        // waves fully independent: NO LDS, NO barriers
    const int l15  = lane & 15;
    const int g    = lane >> 4;
    const int gi   = g * 4;
    const int vecbase = blockIdx.x * 256 + w * 64;   // 64 vectors per wave

    const s16x8* __restrict__ Ap = (const s16x8*)cbA;   // frag idx = t*128 + h*64 + lane

    // ---- prime depth-4 A-frag + ||c||^2 prefetch (in flight during x convert) ----
    s16x8 Afr[4][2];
    f32x4 cnr[4];
    #pragma unroll
    for (int d = 0; d < 4; ++d) {
        Afr[d][0] = Ap[d * 128 + lane];
        Afr[d][1] = Ap[d * 128 + 64 + lane];
        cnr[d]    = *(const f32x4*)(cnf + d * 16 + gi);
    }

    // ---- load 64 vectors, convert to bf16 B-frags, accumulate ||x||^2 ----
    // B[k][n]: lane l holds n=l&15, k=(l>>4)*8+j; half h covers dims h*32..h*32+31
    s16x8 xb[4][2];
    float xnorm[4];
    #pragma unroll
    for (int v = 0; v < 4; ++v) {
        const float4* xp = (const float4*)(inp + (size_t)(vecbase + v * 16 + l15) * DIM);
        float4 a0 = xp[g * 2], a1 = xp[g * 2 + 1];
        float4 a2 = xp[8 + g * 2], a3 = xp[8 + g * 2 + 1];
        float f0[8] = {a0.x, a0.y, a0.z, a0.w, a1.x, a1.y, a1.z, a1.w};
        float f1[8] = {a2.x, a2.y, a2.z, a2.w, a3.x, a3.y, a3.z, a3.w};
        float xn = 0.f;
        unsigned w0[4], w1[4];
        #pragma unroll
        for (int p = 0; p < 4; ++p) {
            xn = fmaf(f0[2*p], f0[2*p], xn);
            xn = fmaf(f0[2*p+1], f0[2*p+1], xn);
            xn = fmaf(f1[2*p], f1[2*p], xn);
            xn = fmaf(f1[2*p+1], f1[2*p+1], xn);
            unsigned r0, r1;
            asm("v_cvt_pk_bf16_f32 %0, %1, %2" : "=v"(r0) : "v"(f0[2*p]), "v"(f0[2*p+1]));
            asm("v_cvt_pk_bf16_f32 %0, %1, %2" : "=v"(r1) : "v"(f1[2*p]), "v"(f1[2*p+1]));
            w0[p] = r0; w1[p] = r1;
        }
        xb[v][0] = *(const s16x8*)w0;
        xb[v][1] = *(const s16x8*)w1;
        xnorm[v] = xn;
    }

    float best[4] = {3.4e38f, 3.4e38f, 3.4e38f, 3.4e38f};

    // ---- full-K sweep, 64 tiles, rotating depth-4 register pipeline ----
    // load->use distance = 3 tile bodies (~450 cy) covers contended L2 latency.
    #pragma unroll 4
    for (int t = 0; t < 64; ++t) {
        const int s = t & 3;                 // compile-time under unroll 4
        s16x8 A0 = Afr[s][0];
        s16x8 A1 = Afr[s][1];
        f32x4 cn4 = cnr[s];
        // refill slot s for tile t+4 (t>=60 over-reads the documented pad)
        Afr[s][0] = Ap[(t + 4) * 128 + lane];
        Afr[s][1] = Ap[(t + 4) * 128 + 64 + lane];
        cnr[s]    = *(const f32x4*)(cnf + (t + 4) * 16 + gi);

        f32x4 acc[4];
        #pragma unroll
        for (int v = 0; v < 4; ++v) acc[v] = cn4;           // acc init = ||c||^2
        #pragma unroll
        for (int v = 0; v < 4; ++v) acc[v] = MFMA16(A0, xb[v][0], acc[v]);
        #pragma unroll
        for (int v = 0; v < 4; ++v) acc[v] = MFMA16(A1, xb[v][1], acc[v]);

        int kb = (t << 4) + gi;
        #pragma unroll
        for (int v = 0; v < 4; ++v) {
            float p0 = __uint_as_float((__float_as_uint(acc[v][0]) & 0xFFFFFC00u) | (unsigned)(kb));
            float p1 = __uint_as_float((__float_as_uint(acc[v][1]) & 0xFFFFFC00u) | (unsigned)(kb + 1));
            float p2 = __uint_as_float((__float_as_uint(acc[v][2]) & 0xFFFFFC00u) | (unsigned)(kb + 2));
            float p3 = __uint_as_float((__float_as_uint(acc[v][3]) & 0xFFFFFC00u) | (unsigned)(kb + 3));
            float p01 = fminf(p0, p1), p23 = fminf(p2, p3);
            best[v] = fminf(fminf(p01, p23), best[v]);
        }
    }

    // ---- reduce across the 4 lane groups (codes split by g); finish ||x||^2 ----
    int bidx[4];
    #pragma unroll
    for (int v = 0; v < 4; ++v) {
        best[v] = fminf(best[v], __shfl_xor(best[v], 16));
        best[v] = fminf(best[v], __shfl_xor(best[v], 32));
        xnorm[v] += __shfl_xor(xnorm[v], 16);
        xnorm[v] += __shfl_xor(xnorm[v], 32);
        bidx[v] = (int)(__float_as_uint(best[v]) & 1023u);
    }

    // ---- coalesced output write: wave region = 64 vectors = 16 KB contiguous ----
    float4* ob4 = (float4*)(out + (size_t)vecbase * DIM);
    float ls = 0.0f;
    #pragma unroll
    for (int v = 0; v < 4; ++v) {
        #pragma unroll
        for (int i = 0; i < 4; ++i) {
            int wv = i * 4 + g;
            int bk = __shfl(bidx[v], wv);
            float4 q = ((const float4*)(cb + (size_t)bk * DIM))[l15];
            ob4[(v * 16 + wv) * 16 + l15] = q;
        }
        if (g == 0) {
            atomicAdd(&counts[bidx[v]], 1u);   // 1024 distinct addresses
            ls += best[v] + xnorm[v];          // min dist = score + ||x||^2
        }
    }

    // ---- per-wave loss partial -> private slot (NO atomic) ----
    #pragma unroll
    for (int off = 32; off > 0; off >>= 1) ls += __shfl_xor(ls, off);
    if (lane == 0) partials[blockIdx.x * 4 + w] = ls;
}

__global__ __launch_bounds__(256) void vq_finalize(float* __restrict__ out,
                                                   const float* __restrict__ partials,
                                                   const unsigned int* __restrict__ counts) {
    __shared__ double red[256];
    double s = 0.0;
    for (int i = threadIdx.x; i < 4096; i += 256) s += (double)partials[i];
    double h = 0.0;
    for (int k = threadIdx.x; k < KCB; k += 256) {
        double p = (double)counts[k] / (double)NVEC;
        h += p * log(p + 1e-10);
    }
    red[threadIdx.x] = s;
    __syncthreads();
    for (int t = 128; t > 0; t >>= 1) {
        if (threadIdx.x < t) red[threadIdx.x] += red[threadIdx.x + t];
        __syncthreads();
    }
    double loss_tot = red[0];
    __syncthreads();
    red[threadIdx.x] = h;
    __syncthreads();
    for (int t = 128; t > 0; t >>= 1) {
        if (threadIdx.x < t) red[threadIdx.x] += red[threadIdx.x + t];
        __syncthreads();
    }
    if (threadIdx.x == 0) {
        out[(size_t)NVEC * DIM]     = (float)(0.25 * loss_tot / (double)((size_t)NVEC * DIM));
        out[(size_t)NVEC * DIM + 1] = (float)exp(-red[0]);
    }
}

extern "C" void kernel_launch(void* const* d_in, const int* in_sizes, int n_in,
                              void* d_out, int out_size, void* d_ws, size_t ws_size,
                              hipStream_t stream) {
    const float* inp = (const float*)d_in[0];   // (64,64,64,64) f32
    const float* cb  = (const float*)d_in[1];   // (1024,64) f32
    float* out = (float*)d_out;

    char* ws = (char*)d_ws;
    unsigned int*   counts   = (unsigned int*)(ws + 0);
    float*          cnf      = (float*)(ws + 4112);
    unsigned short* cbA      = (unsigned short*)(ws + 8224);
    float*          partials = (float*)(ws + 147968);

    vq_prep<<<dim3(32), dim3(256), 0, stream>>>(cb, cbA, cnf, counts);
    vq_main<<<dim3(NVEC / 256), dim3(256), 0, stream>>>(inp, cbA, cnf, cb, out,
                                                        partials, counts);
    vq_finalize<<<dim3(1), dim3(256), 0, stream>>>(out, partials, counts);
}

// Round 11
// 110.226 us; speedup vs baseline: 2.2893x; 1.1311x over previous
//
#include <hip/hip_runtime.h>

#define NVEC (64*64*64)   // 262144 vectors
#define KCB 1024          // codebook size
#define DIM 64            // codebook dim
#define BATCHES 16        // 64-vector batches per block
#define GRID 256          // NVEC / (BATCHES*64)

typedef __attribute__((ext_vector_type(8))) short s16x8;   // 8 x bf16
typedef __attribute__((ext_vector_type(4))) float f32x4;

#define MFMA16(A, B, C) __builtin_amdgcn_mfma_f32_16x16x32_bf16((A), (B), (C), 0, 0, 0)

// ws layout (bytes):
//      0 : uint counts[1024]            (ends 4096, pad to 4112)
//   4112 : float cnf[1024]              (ends 8208, pad to 8224)
//   8224 : ushort cbA[64][2][64][8]     A-frag layout of bf16(-2c), 131072 B, ends 139296
// 139392 : float block_partials[256]    (ends 140416) -- per-block loss, NO atomics

__global__ __launch_bounds__(256) void vq_prep(const float* __restrict__ cb,
                                               unsigned short* __restrict__ cbA,
                                               float* __restrict__ cnf,
                                               unsigned int* __restrict__ counts) {
    int q = blockIdx.x * 256 + threadIdx.x;      // 0..8191
    if (q < 256) ((int4*)counts)[q] = int4{0, 0, 0, 0};   // folded memset
    int t = q >> 7;
    int h = (q >> 6) & 1;
    int l = q & 63;
    int m = t * 16 + (l & 15);
    int d0 = h * 32 + ((l >> 4) & 3) * 8;
    const float* row = cb + (size_t)m * DIM + d0;
    unsigned short* dst = cbA + (size_t)q * 8;
    #pragma unroll
    for (int j = 0; j < 8; ++j) {
        float f = -2.0f * row[j];
        unsigned u = __float_as_uint(f);
        dst[j] = (unsigned short)((u + 0x7fffu + ((u >> 16) & 1u)) >> 16);  // RNE bf16
    }
    if (q < KCB) {
        const float* r2 = cb + (size_t)q * DIM;
        double s = 0.0;
        for (int d = 0; d < DIM; ++d) { double c = (double)r2[d]; s = fma(c, c, s); }
        cnf[q] = (float)s;
    }
}

// 1024 threads = 16 waves; wave wv holds codes [wv*64, wv*64+64) as REGISTER-
// RESIDENT A-frags for the whole kernel. Vectors stream through LDS.
__global__ __launch_bounds__(1024) void vq_main(const float* __restrict__ inp,
                                                const unsigned short* __restrict__ cbA,
                                                const float* __restrict__ cnf,
                                                const float* __restrict__ cb,
                                                float* __restrict__ out,
                                                float* __restrict__ partials,
                                                unsigned int* __restrict__ counts) {
    __shared__ unsigned short xf[2][512][8];   // x B-frags, double-buffered, 16 KB
    __shared__ float xnp[2][512];              // xnorm partials [buf][vec*8+slice], 4 KB
    __shared__ float sred[64][17];             // per-vec per-wave packed best, 4.25 KB
    __shared__ float lossL[64];

    const int tid  = threadIdx.x;
    const int lane = tid & 63;
    const int wv   = tid >> 6;        // wave 0..15 = code slice
    const int l15  = lane & 15;
    const int g    = lane >> 4;
    const int gi   = g * 4;
    const int blockbase = blockIdx.x * (BATCHES * 64);

    // convert-role constants (threads < 512): cell = (vt*2+h)*64 + l
    const int cvt_vt    = tid >> 7;
    const int cvt_h     = (tid >> 6) & 1;
    const int cvt_l     = tid & 63;
    const int cvt_vec   = cvt_vt * 16 + (cvt_l & 15);        // vec-in-batch 0..63
    const int cvt_d0    = cvt_h * 32 + (cvt_l >> 4) * 8;     // first of 8 dims
    const int cvt_slice = cvt_h * 4 + (cvt_l >> 4);          // 0..7

    // ---- issue batch-0 x loads first (longest latency) ----
    float4 x0{}, x1{};
    if (tid < 512) {
        const float* xp = inp + (size_t)(blockbase + cvt_vec) * DIM + cvt_d0;
        x0 = ((const float4*)xp)[0];
        x1 = ((const float4*)xp)[1];
    }

    // ---- load this wave's codebook slice into registers (stays forever) ----
    const s16x8* __restrict__ Ap = (const s16x8*)cbA;
    s16x8 A[4][2];
    f32x4 cn[4];
    #pragma unroll
    for (int tt = 0; tt < 4; ++tt) {
        int T = wv * 4 + tt;
        A[tt][0] = Ap[(T * 2 + 0) * 64 + lane];
        A[tt][1] = Ap[(T * 2 + 1) * 64 + lane];
        cn[tt]   = *(const f32x4*)(cnf + T * 16 + gi);
    }

    float loss_acc = 0.0f;

    for (int b = 0; b < BATCHES; ++b) {
        const int buf = b & 1;
        const int vecbase = blockbase + b * 64;

        // ---- convert phase (threads < 512): x regs -> bf16 frags in LDS ----
        if (tid < 512) {
            float f[8] = {x0.x, x0.y, x0.z, x0.w, x1.x, x1.y, x1.z, x1.w};
            float xn = 0.f;
            unsigned wq[4];
            #pragma unroll
            for (int p = 0; p < 4; ++p) {
                xn = fmaf(f[2*p], f[2*p], xn);
                xn = fmaf(f[2*p+1], f[2*p+1], xn);
                unsigned r;
                asm("v_cvt_pk_bf16_f32 %0, %1, %2" : "=v"(r) : "v"(f[2*p]), "v"(f[2*p+1]));
                wq[p] = r;
            }
            *(int4*)&xf[buf][tid][0] = *(const int4*)wq;
            xnp[buf][cvt_vec * 8 + cvt_slice] = xn;
        }
        __syncthreads();   // frags ready

        // ---- issue next batch's x loads; held in regs across MFMA phase ----
        if (tid < 512 && b + 1 < BATCHES) {
            const float* xp = inp + (size_t)(vecbase + 64 + cvt_vec) * DIM + cvt_d0;
            x0 = ((const float4*)xp)[0];
            x1 = ((const float4*)xp)[1];
        }

        // ---- MFMA + argmin: this wave scores 64 vecs vs its 64 codes ----
        float bestv[4];
        #pragma unroll
        for (int vt = 0; vt < 4; ++vt) {
            s16x8 xb0 = *(const s16x8*)&xf[buf][(vt * 2 + 0) * 64 + lane][0];
            s16x8 xb1 = *(const s16x8*)&xf[buf][(vt * 2 + 1) * 64 + lane][0];
            f32x4 a0 = cn[0], a1 = cn[1], a2 = cn[2], a3 = cn[3];
            a0 = MFMA16(A[0][0], xb0, a0);
            a1 = MFMA16(A[1][0], xb0, a1);
            a2 = MFMA16(A[2][0], xb0, a2);
            a3 = MFMA16(A[3][0], xb0, a3);
            a0 = MFMA16(A[0][1], xb1, a0);
            a1 = MFMA16(A[1][1], xb1, a1);
            a2 = MFMA16(A[2][1], xb1, a2);
            a3 = MFMA16(A[3][1], xb1, a3);

            float bv = 3.4e38f;
            #define PACKMIN(ACC, TT) {                                                        \
                unsigned cbase = (unsigned)(wv * 64 + (TT) * 16 + gi);                        \
                float p0 = __uint_as_float((__float_as_uint(ACC[0]) & 0xFFFFFC00u) | cbase);  \
                float p1 = __uint_as_float((__float_as_uint(ACC[1]) & 0xFFFFFC00u) | (cbase+1));\
                float p2 = __uint_as_float((__float_as_uint(ACC[2]) & 0xFFFFFC00u) | (cbase+2));\
                float p3 = __uint_as_float((__float_as_uint(ACC[3]) & 0xFFFFFC00u) | (cbase+3));\
                bv = fminf(bv, fminf(fminf(p0, p1), fminf(p2, p3))); }
            PACKMIN(a0, 0) PACKMIN(a1, 1) PACKMIN(a2, 2) PACKMIN(a3, 3)
            #undef PACKMIN
            bestv[vt] = bv;
        }

        // cross-lane-group combine (codes split across g), then publish per-wave best
        #pragma unroll
        for (int vt = 0; vt < 4; ++vt) {
            bestv[vt] = fminf(bestv[vt], __shfl_xor(bestv[vt], 16));
            bestv[vt] = fminf(bestv[vt], __shfl_xor(bestv[vt], 32));
        }
        if (g == 0) {
            #pragma unroll
            for (int vt = 0; vt < 4; ++vt) sred[vt * 16 + l15][wv] = bestv[vt];
        }
        __syncthreads();   // sred ready

        // ---- final 16-way reduce + coalesced epilogue (all 1024 threads) ----
        {
            const int vec = tid >> 4, sl = tid & 15;
            float pb = sred[vec][sl];
            pb = fminf(pb, __shfl_xor(pb, 1));
            pb = fminf(pb, __shfl_xor(pb, 2));
            pb = fminf(pb, __shfl_xor(pb, 4));
            pb = fminf(pb, __shfl_xor(pb, 8));
            int bk = (int)(__float_as_uint(pb) & 1023u);
            float4 q = ((const float4*)cb)[bk * 16 + sl];
            ((float4*)out)[(size_t)(vecbase + vec) * 16 + sl] = q;
            if (sl == 0) {
                float xn = 0.f;
                #pragma unroll
                for (int j = 0; j < 8; ++j) xn += xnp[buf][vec * 8 + j];
                loss_acc += pb + xn;          // min dist = packed score + ||x||^2
                atomicAdd(&counts[bk], 1u);
            }
        }
        // no barrier: next convert writes xf/xnp[buf^1]; sred next written only
        // after the next post-convert barrier.
    }

    // ---- block loss reduction -> one partial per block ----
    if ((tid & 15) == 0) lossL[tid >> 4] = loss_acc;
    __syncthreads();
    if (tid < 64) {
        float v = lossL[tid];
        #pragma unroll
        for (int off = 32; off > 0; off >>= 1) v += __shfl_xor(v, off);
        if (tid == 0) partials[blockIdx.x] = v;
    }
}

__global__ __launch_bounds__(256) void vq_finalize(float* __restrict__ out,
                                                   const float* __restrict__ partials,
                                                   const unsigned int* __restrict__ counts) {
    __shared__ double red[256];
    double s = (threadIdx.x < GRID) ? (double)partials[threadIdx.x] : 0.0;
    double h = 0.0;
    for (int k = threadIdx.x; k < KCB; k += 256) {
        double p = (double)counts[k] / (double)NVEC;
        h += p * log(p + 1e-10);
    }
    red[threadIdx.x] = s;
    __syncthreads();
    for (int t = 128; t > 0; t >>= 1) {
        if (threadIdx.x < t) red[threadIdx.x] += red[threadIdx.x + t];
        __syncthreads();
    }
    double loss_tot = red[0];
    __syncthreads();
    red[threadIdx.x] = h;
    __syncthreads();
    for (int t = 128; t > 0; t >>= 1) {
        if (threadIdx.x < t) red[threadIdx.x] += red[threadIdx.x + t];
        __syncthreads();
    }
    if (threadIdx.x == 0) {
        out[(size_t)NVEC * DIM]     = (float)(0.25 * loss_tot / (double)((size_t)NVEC * DIM));
        out[(size_t)NVEC * DIM + 1] = (float)exp(-red[0]);
    }
}

extern "C" void kernel_launch(void* const* d_in, const int* in_sizes, int n_in,
                              void* d_out, int out_size, void* d_ws, size_t ws_size,
                              hipStream_t stream) {
    const float* inp = (const float*)d_in[0];   // (64,64,64,64) f32
    const float* cb  = (const float*)d_in[1];   // (1024,64) f32
    float* out = (float*)d_out;

    char* ws = (char*)d_ws;
    unsigned int*   counts   = (unsigned int*)(ws + 0);
    float*          cnf      = (float*)(ws + 4112);
    unsigned short* cbA      = (unsigned short*)(ws + 8224);
    float*          partials = (float*)(ws + 139392);

    vq_prep<<<dim3(32), dim3(256), 0, stream>>>(cb, cbA, cnf, counts);
    vq_main<<<dim3(GRID), dim3(1024), 0, stream>>>(inp, cbA, cnf, cb, out,
                                                   partials, counts);
    vq_finalize<<<dim3(1), dim3(256), 0, stream>>>(out, partials, counts);
}

// Round 12
// 62.171 us; speedup vs baseline: 4.0589x; 1.7730x over previous
//
#include <hip/hip_runtime.h>

#define NVEC (64*64*64)   // 262144 vectors
#define KCB 1024          // codebook size
#define DIM 64            // codebook dim
#define BATCHES 16        // 64-vector batches per block
#define GRID 256          // NVEC / (BATCHES*64)
#define NSLOT 32          // global count-accumulation slots

typedef __attribute__((ext_vector_type(8))) short s16x8;   // 8 x bf16
typedef __attribute__((ext_vector_type(4))) float f32x4;

#define MFMA16(A, B, C) __builtin_amdgcn_mfma_f32_16x16x32_bf16((A), (B), (C), 0, 0, 0)

// ws layout (bytes):
//      0 : float cnf[1024]                  (ends 4096)
//   4096 : ushort cbA[64][2][64][8]         A-frag bf16(-2c), 131072 B (ends 135168)
// 135168 : float block_partials[256]        (ends 136192) -- per-block loss, NO atomics
// 136192 : uint slots[32][1024]             (ends 267264) -- count accumulators,
//                                           zeroed by vq_prep, 8 RMW/addr only

__global__ __launch_bounds__(256) void vq_prep(const float* __restrict__ cb,
                                               unsigned short* __restrict__ cbA,
                                               float* __restrict__ cnf,
                                               unsigned int* __restrict__ slots) {
    int q = blockIdx.x * 256 + threadIdx.x;      // 0..8191
    ((int4*)slots)[q] = int4{0, 0, 0, 0};         // zero all 32*1024 uints (8192*16B)
    int t = q >> 7;
    int h = (q >> 6) & 1;
    int l = q & 63;
    int m = t * 16 + (l & 15);
    int d0 = h * 32 + ((l >> 4) & 3) * 8;
    const float* row = cb + (size_t)m * DIM + d0;
    unsigned short* dst = cbA + (size_t)q * 8;
    #pragma unroll
    for (int j = 0; j < 8; ++j) {
        float f = -2.0f * row[j];
        unsigned u = __float_as_uint(f);
        dst[j] = (unsigned short)((u + 0x7fffu + ((u >> 16) & 1u)) >> 16);  // RNE bf16
    }
    if (q < KCB) {
        const float* r2 = cb + (size_t)q * DIM;
        double s = 0.0;
        for (int d = 0; d < DIM; ++d) { double c = (double)r2[d]; s = fma(c, c, s); }
        cnf[q] = (float)s;
    }
}

// 1024 threads = 16 waves; wave wv holds codes [wv*64, wv*64+64) REGISTER-
// RESIDENT for the whole kernel. Vectors stream through LDS. Counts go to an
// LDS histogram -> 1 global fold per block (NO per-vector global atomics).
__global__ __launch_bounds__(1024) void vq_main(const float* __restrict__ inp,
                                                const unsigned short* __restrict__ cbA,
                                                const float* __restrict__ cnf,
                                                const float* __restrict__ cb,
                                                float* __restrict__ out,
                                                float* __restrict__ partials,
                                                unsigned int* __restrict__ slots) {
    __shared__ unsigned short xf[2][512][8];   // x B-frags, double-buffered, 16 KB
    __shared__ float xnp[2][512];              // xnorm partials, 4 KB
    __shared__ float sred[64][17];             // per-vec per-wave packed best, 4.25 KB
    __shared__ unsigned int histS[KCB];        // per-block count histogram, 4 KB
    __shared__ float lossL[64];

    const int tid  = threadIdx.x;
    const int lane = tid & 63;
    const int wv   = tid >> 6;        // wave 0..15 = code slice
    const int l15  = lane & 15;
    const int g    = lane >> 4;
    const int gi   = g * 4;
    const int blockbase = blockIdx.x * (BATCHES * 64);

    // convert-role constants (threads < 512): cell = (vt*2+h)*64 + l
    const int cvt_vt    = tid >> 7;
    const int cvt_h     = (tid >> 6) & 1;
    const int cvt_l     = tid & 63;
    const int cvt_vec   = cvt_vt * 16 + (cvt_l & 15);        // vec-in-batch 0..63
    const int cvt_d0    = cvt_h * 32 + (cvt_l >> 4) * 8;     // first of 8 dims
    const int cvt_slice = cvt_h * 4 + (cvt_l >> 4);          // 0..7

    histS[tid] = 0u;   // covers all 1024 counters (barrier below orders first use)

    // ---- issue batch-0 x loads first (longest latency) ----
    float4 x0{}, x1{};
    if (tid < 512) {
        const float* xp = inp + (size_t)(blockbase + cvt_vec) * DIM + cvt_d0;
        x0 = ((const float4*)xp)[0];
        x1 = ((const float4*)xp)[1];
    }

    // ---- load this wave's codebook slice into registers (stays forever) ----
    const s16x8* __restrict__ Ap = (const s16x8*)cbA;
    s16x8 A[4][2];
    f32x4 cn[4];
    #pragma unroll
    for (int tt = 0; tt < 4; ++tt) {
        int T = wv * 4 + tt;
        A[tt][0] = Ap[(T * 2 + 0) * 64 + lane];
        A[tt][1] = Ap[(T * 2 + 1) * 64 + lane];
        cn[tt]   = *(const f32x4*)(cnf + T * 16 + gi);
    }

    float loss_acc = 0.0f;

    for (int b = 0; b < BATCHES; ++b) {
        const int buf = b & 1;
        const int vecbase = blockbase + b * 64;

        // ---- convert phase (threads < 512): x regs -> bf16 frags in LDS ----
        if (tid < 512) {
            float f[8] = {x0.x, x0.y, x0.z, x0.w, x1.x, x1.y, x1.z, x1.w};
            float xn = 0.f;
            unsigned wq[4];
            #pragma unroll
            for (int p = 0; p < 4; ++p) {
                xn = fmaf(f[2*p], f[2*p], xn);
                xn = fmaf(f[2*p+1], f[2*p+1], xn);
                unsigned r;
                asm("v_cvt_pk_bf16_f32 %0, %1, %2" : "=v"(r) : "v"(f[2*p]), "v"(f[2*p+1]));
                wq[p] = r;
            }
            *(int4*)&xf[buf][tid][0] = *(const int4*)wq;
            xnp[buf][cvt_vec * 8 + cvt_slice] = xn;
        }
        __syncthreads();   // frags ready (also orders histS init before batch 0 use)

        // ---- issue next batch's x loads; held in regs across MFMA phase ----
        if (tid < 512 && b + 1 < BATCHES) {
            const float* xp = inp + (size_t)(vecbase + 64 + cvt_vec) * DIM + cvt_d0;
            x0 = ((const float4*)xp)[0];
            x1 = ((const float4*)xp)[1];
        }

        // ---- MFMA + argmin: this wave scores 64 vecs vs its 64 codes ----
        float bestv[4];
        #pragma unroll
        for (int vt = 0; vt < 4; ++vt) {
            s16x8 xb0 = *(const s16x8*)&xf[buf][(vt * 2 + 0) * 64 + lane][0];
            s16x8 xb1 = *(const s16x8*)&xf[buf][(vt * 2 + 1) * 64 + lane][0];
            f32x4 a0 = cn[0], a1 = cn[1], a2 = cn[2], a3 = cn[3];
            a0 = MFMA16(A[0][0], xb0, a0);
            a1 = MFMA16(A[1][0], xb0, a1);
            a2 = MFMA16(A[2][0], xb0, a2);
            a3 = MFMA16(A[3][0], xb0, a3);
            a0 = MFMA16(A[0][1], xb1, a0);
            a1 = MFMA16(A[1][1], xb1, a1);
            a2 = MFMA16(A[2][1], xb1, a2);
            a3 = MFMA16(A[3][1], xb1, a3);

            float bv = 3.4e38f;
            #define PACKMIN(ACC, TT) {                                                        \
                unsigned cbase = (unsigned)(wv * 64 + (TT) * 16 + gi);                        \
                float p0 = __uint_as_float((__float_as_uint(ACC[0]) & 0xFFFFFC00u) | cbase);  \
                float p1 = __uint_as_float((__float_as_uint(ACC[1]) & 0xFFFFFC00u) | (cbase+1));\
                float p2 = __uint_as_float((__float_as_uint(ACC[2]) & 0xFFFFFC00u) | (cbase+2));\
                float p3 = __uint_as_float((__float_as_uint(ACC[3]) & 0xFFFFFC00u) | (cbase+3));\
                bv = fminf(bv, fminf(fminf(p0, p1), fminf(p2, p3))); }
            PACKMIN(a0, 0) PACKMIN(a1, 1) PACKMIN(a2, 2) PACKMIN(a3, 3)
            #undef PACKMIN
            bestv[vt] = bv;
        }

        // cross-lane-group combine (codes split across g), publish per-wave best
        #pragma unroll
        for (int vt = 0; vt < 4; ++vt) {
            bestv[vt] = fminf(bestv[vt], __shfl_xor(bestv[vt], 16));
            bestv[vt] = fminf(bestv[vt], __shfl_xor(bestv[vt], 32));
        }
        if (g == 0) {
            #pragma unroll
            for (int vt = 0; vt < 4; ++vt) sred[vt * 16 + l15][wv] = bestv[vt];
        }
        __syncthreads();   // sred ready

        // ---- final 16-way reduce + coalesced epilogue (all 1024 threads) ----
        {
            const int vec = tid >> 4, sl = tid & 15;
            float pb = sred[vec][sl];
            pb = fminf(pb, __shfl_xor(pb, 1));
            pb = fminf(pb, __shfl_xor(pb, 2));
            pb = fminf(pb, __shfl_xor(pb, 4));
            pb = fminf(pb, __shfl_xor(pb, 8));
            int bk = (int)(__float_as_uint(pb) & 1023u);
            float4 q = ((const float4*)cb)[bk * 16 + sl];
            ((float4*)out)[(size_t)(vecbase + vec) * 16 + sl] = q;
            if (sl == 0) {
                float xn = 0.f;
                #pragma unroll
                for (int j = 0; j < 8; ++j) xn += xnp[buf][vec * 8 + j];
                loss_acc += pb + xn;               // min dist = packed score + ||x||^2
                atomicAdd(&histS[bk], 1u);         // LDS atomic -- no global RMW
            }
        }
        // no barrier: next convert writes xf/xnp[buf^1]; sred rewritten only
        // after the next post-convert barrier.
    }

    // ---- block loss reduction + histogram fold-out ----
    if ((tid & 15) == 0) lossL[tid >> 4] = loss_acc;
    __syncthreads();
    if (tid < 64) {
        float v = lossL[tid];
        #pragma unroll
        for (int off = 32; off > 0; off >>= 1) v += __shfl_xor(v, off);
        if (tid == 0) partials[blockIdx.x] = v;
    }
    unsigned hv = histS[tid];
    if (hv) atomicAdd(&slots[(blockIdx.x & (NSLOT - 1)) * KCB + tid], hv);
}

__global__ __launch_bounds__(1024) void vq_finalize(float* __restrict__ out,
                                                    const float* __restrict__ partials,
                                                    const unsigned int* __restrict__ slots) {
    __shared__ double red[1024];
    const int tid = threadIdx.x;
    // total count for code `tid`
    unsigned tot = 0;
    #pragma unroll
    for (int s = 0; s < NSLOT; ++s) tot += slots[s * KCB + tid];
    double p = (double)tot / (double)NVEC;
    double h = p * log(p + 1e-10);
    // loss partial
    double ls = (tid < GRID) ? (double)partials[tid] : 0.0;

    red[tid] = ls;
    __syncthreads();
    for (int t = 512; t > 0; t >>= 1) {
        if (tid < t) red[tid] += red[tid + t];
        __syncthreads();
    }
    double loss_tot = red[0];
    __syncthreads();
    red[tid] = h;
    __syncthreads();
    for (int t = 512; t > 0; t >>= 1) {
        if (tid < t) red[tid] += red[tid + t];
        __syncthreads();
    }
    if (tid == 0) {
        out[(size_t)NVEC * DIM]     = (float)(0.25 * loss_tot / (double)((size_t)NVEC * DIM));
        out[(size_t)NVEC * DIM + 1] = (float)exp(-red[0]);
    }
}

extern "C" void kernel_launch(void* const* d_in, const int* in_sizes, int n_in,
                              void* d_out, int out_size, void* d_ws, size_t ws_size,
                              hipStream_t stream) {
    const float* inp = (const float*)d_in[0];   // (64,64,64,64) f32
    const float* cb  = (const float*)d_in[1];   // (1024,64) f32
    float* out = (float*)d_out;

    char* ws = (char*)d_ws;
    float*          cnf      = (float*)(ws + 0);
    unsigned short* cbA      = (unsigned short*)(ws + 4096);
    float*          partials = (float*)(ws + 135168);
    unsigned int*   slots    = (unsigned int*)(ws + 136192);

    vq_prep<<<dim3(32), dim3(256), 0, stream>>>(cb, cbA, cnf, slots);
    vq_main<<<dim3(GRID), dim3(1024), 0, stream>>>(inp, cbA, cnf, cb, out,
                                                   partials, slots);
    vq_finalize<<<dim3(1), dim3(1024), 0, stream>>>(out, partials, slots);
}

// Round 13
// 61.760 us; speedup vs baseline: 4.0859x; 1.0066x over previous
//
#include <hip/hip_runtime.h>

#define NVEC (64*64*64)   // 262144 vectors
#define KCB 1024          // codebook size
#define DIM 64            // codebook dim
#define VB 128            // vectors per batch
#define BATCHES 8         // batches per block
#define GRID 256          // NVEC / (BATCHES*VB)
#define NSLOT 32          // global count-accumulation slots

typedef __attribute__((ext_vector_type(8))) short s16x8;   // 8 x bf16
typedef __attribute__((ext_vector_type(4))) float f32x4;

#define MFMA16(A, B, C) __builtin_amdgcn_mfma_f32_16x16x32_bf16((A), (B), (C), 0, 0, 0)

// ws layout (bytes):
//      0 : float cnf[1024]                  (ends 4096)
//   4096 : ushort cbA[64][2][64][8]         A-frag bf16(-2c), 131072 B (ends 135168)
// 135168 : float block_partials[256]        (ends 136192) -- per-block loss, NO atomics
// 136192 : uint slots[32][1024]             (ends 267264) -- count accumulators,
//                                           zeroed by vq_prep, 8 RMW/addr only

__global__ __launch_bounds__(256) void vq_prep(const float* __restrict__ cb,
                                               unsigned short* __restrict__ cbA,
                                               float* __restrict__ cnf,
                                               unsigned int* __restrict__ slots) {
    int q = blockIdx.x * 256 + threadIdx.x;      // 0..8191
    ((int4*)slots)[q] = int4{0, 0, 0, 0};         // zero all 32*1024 uints
    int t = q >> 7;
    int h = (q >> 6) & 1;
    int l = q & 63;
    int m = t * 16 + (l & 15);
    int d0 = h * 32 + ((l >> 4) & 3) * 8;
    const float* row = cb + (size_t)m * DIM + d0;
    unsigned short* dst = cbA + (size_t)q * 8;
    #pragma unroll
    for (int j = 0; j < 8; ++j) {
        float f = -2.0f * row[j];
        unsigned u = __float_as_uint(f);
        dst[j] = (unsigned short)((u + 0x7fffu + ((u >> 16) & 1u)) >> 16);  // RNE bf16
    }
    if (q < KCB) {
        const float* r2 = cb + (size_t)q * DIM;
        double s = 0.0;
        for (int d = 0; d < DIM; ++d) { double c = (double)r2[d]; s = fma(c, c, s); }
        cnf[q] = (float)s;
    }
}

// 1024 threads = 16 waves; wave wv holds codes [wv*64, wv*64+64) REGISTER-
// RESIDENT. 128-vector batches: 8 batches x 2 barriers = 16 rendezvous total
// (vs 32 in round 12); all 1024 threads convert; 8 vt per MFMA phase.
__global__ __launch_bounds__(1024) void vq_main(const float* __restrict__ inp,
                                                const unsigned short* __restrict__ cbA,
                                                const float* __restrict__ cnf,
                                                const float* __restrict__ cb,
                                                float* __restrict__ out,
                                                float* __restrict__ partials,
                                                unsigned int* __restrict__ slots) {
    __shared__ unsigned short xf[2][1024][8];  // x B-frags, double-buffered, 32 KB
    __shared__ float xnp[2][1024];             // xnorm partials, 8 KB
    __shared__ float sred[VB][17];             // per-vec per-wave packed best, 8.5 KB
    __shared__ unsigned int histS[KCB];        // per-block count histogram, 4 KB
    __shared__ float lossL[64];

    const int tid  = threadIdx.x;
    const int lane = tid & 63;
    const int wv   = tid >> 6;        // wave 0..15 = code slice
    const int l15  = lane & 15;
    const int g    = lane >> 4;
    const int gi   = g * 4;
    const int blockbase = blockIdx.x * (BATCHES * VB);

    // convert-role constants (ALL 1024 threads): cell tid = (vt*2+h)*64 + l
    const int cvt_vt    = tid >> 7;                          // 0..7
    const int cvt_h     = (tid >> 6) & 1;
    const int cvt_l     = tid & 63;
    const int cvt_vec   = cvt_vt * 16 + (cvt_l & 15);        // vec-in-batch 0..127
    const int cvt_d0    = cvt_h * 32 + (cvt_l >> 4) * 8;     // first of 8 dims
    const int cvt_slice = cvt_h * 4 + (cvt_l >> 4);          // 0..7

    histS[tid] = 0u;   // barrier below orders first use

    // ---- issue batch-0 x loads first (longest latency) ----
    float4 x0{}, x1{};
    {
        const float* xp = inp + (size_t)(blockbase + cvt_vec) * DIM + cvt_d0;
        x0 = ((const float4*)xp)[0];
        x1 = ((const float4*)xp)[1];
    }

    // ---- load this wave's codebook slice into registers (stays forever) ----
    const s16x8* __restrict__ Ap = (const s16x8*)cbA;
    s16x8 A[4][2];
    f32x4 cn[4];
    #pragma unroll
    for (int tt = 0; tt < 4; ++tt) {
        int T = wv * 4 + tt;
        A[tt][0] = Ap[(T * 2 + 0) * 64 + lane];
        A[tt][1] = Ap[(T * 2 + 1) * 64 + lane];
        cn[tt]   = *(const f32x4*)(cnf + T * 16 + gi);
    }

    float loss_acc = 0.0f;

    for (int b = 0; b < BATCHES; ++b) {
        const int buf = b & 1;
        const int vecbase = blockbase + b * VB;

        // ---- convert phase (all threads): x regs -> bf16 frags in LDS ----
        {
            float f[8] = {x0.x, x0.y, x0.z, x0.w, x1.x, x1.y, x1.z, x1.w};
            float xn = 0.f;
            unsigned wq[4];
            #pragma unroll
            for (int p = 0; p < 4; ++p) {
                xn = fmaf(f[2*p], f[2*p], xn);
                xn = fmaf(f[2*p+1], f[2*p+1], xn);
                unsigned r;
                asm("v_cvt_pk_bf16_f32 %0, %1, %2" : "=v"(r) : "v"(f[2*p]), "v"(f[2*p+1]));
                wq[p] = r;
            }
            *(int4*)&xf[buf][tid][0] = *(const int4*)wq;
            xnp[buf][cvt_vec * 8 + cvt_slice] = xn;
        }
        __syncthreads();   // frags ready

        // ---- issue next batch's x loads; held in regs across MFMA phase ----
        if (b + 1 < BATCHES) {
            const float* xp = inp + (size_t)(vecbase + VB + cvt_vec) * DIM + cvt_d0;
            x0 = ((const float4*)xp)[0];
            x1 = ((const float4*)xp)[1];
        }

        // ---- MFMA + argmin: this wave scores 128 vecs vs its 64 codes ----
        float bestv[8];
        #pragma unroll
        for (int vt = 0; vt < 8; ++vt) {
            s16x8 xb0 = *(const s16x8*)&xf[buf][(vt * 2 + 0) * 64 + lane][0];
            s16x8 xb1 = *(const s16x8*)&xf[buf][(vt * 2 + 1) * 64 + lane][0];
            f32x4 a0 = cn[0], a1 = cn[1], a2 = cn[2], a3 = cn[3];
            a0 = MFMA16(A[0][0], xb0, a0);
            a1 = MFMA16(A[1][0], xb0, a1);
            a2 = MFMA16(A[2][0], xb0, a2);
            a3 = MFMA16(A[3][0], xb0, a3);
            a0 = MFMA16(A[0][1], xb1, a0);
            a1 = MFMA16(A[1][1], xb1, a1);
            a2 = MFMA16(A[2][1], xb1, a2);
            a3 = MFMA16(A[3][1], xb1, a3);

            float bv = 3.4e38f;
            #define PACKMIN(ACC, TT) {                                                        \
                unsigned cbase = (unsigned)(wv * 64 + (TT) * 16 + gi);                        \
                float p0 = __uint_as_float((__float_as_uint(ACC[0]) & 0xFFFFFC00u) | cbase);  \
                float p1 = __uint_as_float((__float_as_uint(ACC[1]) & 0xFFFFFC00u) | (cbase+1));\
                float p2 = __uint_as_float((__float_as_uint(ACC[2]) & 0xFFFFFC00u) | (cbase+2));\
                float p3 = __uint_as_float((__float_as_uint(ACC[3]) & 0xFFFFFC00u) | (cbase+3));\
                bv = fminf(bv, fminf(fminf(p0, p1), fminf(p2, p3))); }
            PACKMIN(a0, 0) PACKMIN(a1, 1) PACKMIN(a2, 2) PACKMIN(a3, 3)
            #undef PACKMIN
            bestv[vt] = bv;
        }

        // cross-lane-group combine (codes split across g), publish per-wave best
        #pragma unroll
        for (int vt = 0; vt < 8; ++vt) {
            bestv[vt] = fminf(bestv[vt], __shfl_xor(bestv[vt], 16));
            bestv[vt] = fminf(bestv[vt], __shfl_xor(bestv[vt], 32));
        }
        if (g == 0) {
            #pragma unroll
            for (int vt = 0; vt < 8; ++vt) sred[vt * 16 + l15][wv] = bestv[vt];
        }
        __syncthreads();   // sred ready

        // ---- final 16-way reduce + coalesced epilogue (2 reps x 64 vecs) ----
        #pragma unroll
        for (int rep = 0; rep < 2; ++rep) {
            const int vec = rep * 64 + (tid >> 4), sl = tid & 15;
            float pb = sred[vec][sl];
            pb = fminf(pb, __shfl_xor(pb, 1));
            pb = fminf(pb, __shfl_xor(pb, 2));
            pb = fminf(pb, __shfl_xor(pb, 4));
            pb = fminf(pb, __shfl_xor(pb, 8));
            int bk = (int)(__float_as_uint(pb) & 1023u);
            float4 q = ((const float4*)cb)[bk * 16 + sl];
            ((float4*)out)[(size_t)(vecbase + vec) * 16 + sl] = q;
            if (sl == 0) {
                float xn = 0.f;
                #pragma unroll
                for (int j = 0; j < 8; ++j) xn += xnp[buf][vec * 8 + j];
                loss_acc += pb + xn;               // min dist = packed score + ||x||^2
                atomicAdd(&histS[bk], 1u);         // LDS atomic -- no global RMW
            }
        }
        // no barrier: next convert writes xf/xnp[buf^1]; sred rewritten only
        // after the next post-convert barrier.
    }

    // ---- block loss reduction + histogram fold-out ----
    if ((tid & 15) == 0) lossL[tid >> 4] = loss_acc;
    __syncthreads();
    if (tid < 64) {
        float v = lossL[tid];
        #pragma unroll
        for (int off = 32; off > 0; off >>= 1) v += __shfl_xor(v, off);
        if (tid == 0) partials[blockIdx.x] = v;
    }
    unsigned hv = histS[tid];
    if (hv) atomicAdd(&slots[(blockIdx.x & (NSLOT - 1)) * KCB + tid], hv);
}

__global__ __launch_bounds__(1024) void vq_finalize(float* __restrict__ out,
                                                    const float* __restrict__ partials,
                                                    const unsigned int* __restrict__ slots) {
    __shared__ double red[1024];
    const int tid = threadIdx.x;
    unsigned tot = 0;
    #pragma unroll
    for (int s = 0; s < NSLOT; ++s) tot += slots[s * KCB + tid];
    double p = (double)tot / (double)NVEC;
    double h = p * log(p + 1e-10);
    double ls = (tid < GRID) ? (double)partials[tid] : 0.0;

    red[tid] = ls;
    __syncthreads();
    for (int t = 512; t > 0; t >>= 1) {
        if (tid < t) red[tid] += red[tid + t];
        __syncthreads();
    }
    double loss_tot = red[0];
    __syncthreads();
    red[tid] = h;
    __syncthreads();
    for (int t = 512; t > 0; t >>= 1) {
        if (tid < t) red[tid] += red[tid + t];
        __syncthreads();
    }
    if (tid == 0) {
        out[(size_t)NVEC * DIM]     = (float)(0.25 * loss_tot / (double)((size_t)NVEC * DIM));
        out[(size_t)NVEC * DIM + 1] = (float)exp(-red[0]);
    }
}

extern "C" void kernel_launch(void* const* d_in, const int* in_sizes, int n_in,
                              void* d_out, int out_size, void* d_ws, size_t ws_size,
                              hipStream_t stream) {
    const float* inp = (const float*)d_in[0];   // (64,64,64,64) f32
    const float* cb  = (const float*)d_in[1];   // (1024,64) f32
    float* out = (float*)d_out;

    char* ws = (char*)d_ws;
    float*          cnf      = (float*)(ws + 0);
    unsigned short* cbA      = (unsigned short*)(ws + 4096);
    float*          partials = (float*)(ws + 135168);
    unsigned int*   slots    = (unsigned int*)(ws + 136192);

    vq_prep<<<dim3(32), dim3(256), 0, stream>>>(cb, cbA, cnf, slots);
    vq_main<<<dim3(GRID), dim3(1024), 0, stream>>>(inp, cbA, cnf, cb, out,
                                                   partials, slots);
    vq_finalize<<<dim3(1), dim3(1024), 0, stream>>>(out, partials, slots);
}